// Round 1
// baseline (177.851 us; speedup 1.0000x reference)
//
#include <hip/hip_runtime.h>
#include <stdint.h>

#define B_ 32
#define E_ 256
#define L_ 2048
#define D_ 256

#define BE 128             // e-rows per block
#define BD 256             // d-cols per block (full D)
#define BK 32              // k per LDS tile
#define KS 4               // k-split factor
#define KCHUNK (L_ / KS)   // 512
#define NKT (KCHUNK / BK)  // 16 k-steps per block

typedef __attribute__((ext_vector_type(2))) float  f32x2;
typedef __attribute__((ext_vector_type(4))) float  f32x4;
typedef __attribute__((ext_vector_type(4))) short  s16x4;
typedef __attribute__((ext_vector_type(8))) short  s16x8;

// 3-bit row keys XORed into the 16B-octet index of a 128B LDS row.
// KEYA: bijective on 0..7 over any 8 consecutive rows AND over the 8 rows
//       (stride 1) a staging wave writes -> both sides conflict-free.
// KEYB: (row>>1)&7 -> uniform for B's d-pair staging writes (dp&7 spans 0..7
//       across lanes) and 2-to-1 over any 16 consecutive read rows.
#define KEYA(row) ((((row) >> 1) & 3) | (((row) & 1) << 2))
#define KEYB(row) (((row) >> 1) & 7)

// fp32 -> (hi, lo) bf16 pair. hi = truncated bf16(x); lo = bf16(x - hi).
__device__ __forceinline__ void cvt_hilo1(float x, short &h, short &l) {
    unsigned u = __builtin_bit_cast(unsigned, x);
    h = (short)(u >> 16);
    float hf = __builtin_bit_cast(float, u & 0xFFFF0000u);
    unsigned r = __builtin_bit_cast(unsigned, x - hf);
    l = (short)(r >> 16);
}

__global__ void zero_out_kernel(f32x4* __restrict__ out) {
    out[(size_t)blockIdx.x * 256 + threadIdx.x] = f32x4{0.f, 0.f, 0.f, 0.f};
}

__global__ __launch_bounds__(512, 2)
void mean_pool_kernel(const float* __restrict__ doc,
                      const float* __restrict__ emap,
                      const float* __restrict__ lens,
                      float* __restrict__ out) {
    // 128B LDS row = 8 x 16B octets: [hi k-octets 0..3 | lo k-octets 4..7],
    // octet index XOR-swizzled by row key (conflict-free writes AND reads).
    __shared__ __align__(16) short As[2][BE][64];   // 32 KB
    __shared__ __align__(16) short Bs[2][BD][64];   // 64 KB
    __shared__ float lens_s[BE];

    const int t   = threadIdx.x;
    const int blk = blockIdx.x;
    const int ks  = blk & 3;
    const int e0  = ((blk >> 2) & 1) * BE;
    const int b   = blk >> 3;

    const float* Ag = emap + ((size_t)b * E_ + e0) * L_ + ks * KCHUNK;
    const float* Sg = doc  + (size_t)b * L_ * D_ + (size_t)ks * KCHUNK * D_;

    if (t < BE) lens_s[t] = lens[b * E_ + e0 + t];

    // ---- staging coords ----
    const int a_c4 = t & 7;      // k half-octet (4 floats); 8 lanes/row -> 128B coalesced
    const int a_r  = t >> 3;     // e-rows a_r, a_r+64
    const int dp   = t & 127;    // d-pair: d = 2dp, 2dp+1; 64 lanes -> 512B coalesced
    const int kb   = t >> 7;     // k-octet 0..3

    // ---- wave/MFMA coords: 8 waves as 2(e) x 4(d), wave tile 64x64 ----
    const int lane = t & 63;
    const int w    = t >> 6;
    const int eo   = (w & 1) * 64;
    const int dq   = (w >> 1) * 64;
    const int ml   = lane & 15;
    const int kg   = lane >> 4;

    // ---- precomputed LDS short-offsets (all thread-invariant) ----
    int awo_h[2], awo_l[2];
    #pragma unroll
    for (int rr = 0; rr < 2; ++rr) {
        const int row = a_r + rr * 64, k = KEYA(row), hb = (a_c4 & 1) * 4;
        awo_h[rr] = row * 64 + ((((a_c4 >> 1)    ) ^ k) << 3) + hb;
        awo_l[rr] = row * 64 + ((((a_c4 >> 1) | 4) ^ k) << 3) + hb;
    }
    int bwo_h[2], bwo_l[2];
    #pragma unroll
    for (int dd = 0; dd < 2; ++dd) {
        const int row = dp * 2 + dd, k = KEYB(row);
        bwo_h[dd] = row * 64 + (((kb    ) ^ k) << 3);
        bwo_l[dd] = row * 64 + (((kb | 4) ^ k) << 3);
    }
    int aro_h[4], aro_l[4], bro_h[4], bro_l[4];
    #pragma unroll
    for (int i = 0; i < 4; ++i) {
        const int ar = eo + i * 16 + ml, ka = KEYA(ar);
        aro_h[i] = ar * 64 + (((kg    ) ^ ka) << 3);
        aro_l[i] = ar * 64 + (((kg | 4) ^ ka) << 3);
        const int br = dq + i * 16 + ml, kB = KEYB(br);
        bro_h[i] = br * 64 + (((kg    ) ^ kB) << 3);
        bro_l[i] = br * 64 + (((kg | 4) ^ kB) << 3);
    }

    f32x4 acc[4][4] = {};
    f32x4 pa[2];
    f32x2 pb[8];

    // ---- preload k-tile 0 ----
    #pragma unroll
    for (int rr = 0; rr < 2; ++rr)
        pa[rr] = *(const f32x4*)(Ag + (size_t)(a_r + rr * 64) * L_ + a_c4 * 4);
    #pragma unroll
    for (int j = 0; j < 8; ++j)
        pb[j] = *(const f32x2*)(Sg + (size_t)(kb * 8 + j) * D_ + dp * 2);

    #pragma unroll 2
    for (int kt = 0; kt < NKT; ++kt) {
        short* Ab = &As[kt & 1][0][0];
        short* Bb = &Bs[kt & 1][0][0];

        // ---- convert + stage current tile into LDS buf ----
        #pragma unroll
        for (int rr = 0; rr < 2; ++rr) {
            s16x4 h, l;
            #pragma unroll
            for (int i = 0; i < 4; ++i) { short hh, ll; cvt_hilo1(pa[rr][i], hh, ll); h[i] = hh; l[i] = ll; }
            *(s16x4*)&Ab[awo_h[rr]] = h;
            *(s16x4*)&Ab[awo_l[rr]] = l;
        }
        #pragma unroll
        for (int dd = 0; dd < 2; ++dd) {
            s16x8 h, l;
            #pragma unroll
            for (int j = 0; j < 8; ++j) { short hh, ll; cvt_hilo1(pb[j][dd], hh, ll); h[j] = hh; l[j] = ll; }
            *(s16x8*)&Bb[bwo_h[dd]] = h;
            *(s16x8*)&Bb[bwo_l[dd]] = l;
        }
        // Single barrier per k-step: double buffering means a buffer's rewrite
        // is always separated from its last read by one intervening barrier
        // (whose lgkmcnt(0) drain also completes outstanding ds_reads).
        __syncthreads();

        // ---- issue next tile's global loads; they land under the MFMAs ----
        if (kt + 1 < NKT) {
            const int k0 = (kt + 1) * BK;
            #pragma unroll
            for (int rr = 0; rr < 2; ++rr)
                pa[rr] = *(const f32x4*)(Ag + (size_t)(a_r + rr * 64) * L_ + k0 + a_c4 * 4);
            #pragma unroll
            for (int j = 0; j < 8; ++j)
                pb[j] = *(const f32x2*)(Sg + (size_t)(k0 + kb * 8 + j) * D_ + dp * 2);
        }

        // ---- MFMA: 4x4 frags, 3-pass hi/lo (48 MFMAs per 16 frag-reads) ----
        s16x8 bh[4], bl[4];
        #pragma unroll
        for (int ni = 0; ni < 4; ++ni) {
            bh[ni] = *(const s16x8*)&Bb[bro_h[ni]];
            bl[ni] = *(const s16x8*)&Bb[bro_l[ni]];
        }
        __builtin_amdgcn_s_setprio(1);
        #pragma unroll
        for (int mi = 0; mi < 4; ++mi) {
            const s16x8 ah = *(const s16x8*)&Ab[aro_h[mi]];
            const s16x8 al = *(const s16x8*)&Ab[aro_l[mi]];
            #pragma unroll
            for (int ni = 0; ni < 4; ++ni) {
                acc[mi][ni] = __builtin_amdgcn_mfma_f32_16x16x32_bf16(ah, bh[ni], acc[mi][ni], 0, 0, 0);
                acc[mi][ni] = __builtin_amdgcn_mfma_f32_16x16x32_bf16(ah, bl[ni], acc[mi][ni], 0, 0, 0);
                acc[mi][ni] = __builtin_amdgcn_mfma_f32_16x16x32_bf16(al, bh[ni], acc[mi][ni], 0, 0, 0);
            }
        }
        __builtin_amdgcn_s_setprio(0);
    }

    // ---- epilogue: divide by entity_lens, accumulate k-split partials ----
    #pragma unroll
    for (int mi = 0; mi < 4; ++mi) {
        #pragma unroll
        for (int rr = 0; rr < 4; ++rr) {
            const int er = eo + mi * 16 + kg * 4 + rr;
            const float lv = lens_s[er];
            #pragma unroll
            for (int ni = 0; ni < 4; ++ni)
                atomicAdd(&out[((size_t)(b * E_ + e0 + er)) * D_ + dq + ni * 16 + ml],
                          acc[mi][ni][rr] / lv);
        }
    }
}

extern "C" void kernel_launch(void* const* d_in, const int* in_sizes, int n_in,
                              void* d_out, int out_size, void* d_ws, size_t ws_size,
                              hipStream_t stream) {
    const float* doc  = (const float*)d_in[0];   // [32][2048][256]
    const float* emap = (const float*)d_in[1];   // [32][256][2048]
    const float* lens = (const float*)d_in[2];   // [32][256]
    float* out = (float*)d_out;                  // [32][256][256]

    // zero the output (harness poisons it), then accumulate partials
    zero_out_kernel<<<dim3(out_size / (4 * 256)), dim3(256), 0, stream>>>((f32x4*)out);

    dim3 grid(B_ * (E_ / BE) * (D_ / BD) * KS);  // 256 workgroups, 1 per CU
    dim3 block(512);
    hipLaunchKernelGGL(mean_pool_kernel, grid, block, 0, stream,
                       doc, emap, lens, out);
}

// Round 2
// 176.760 us; speedup vs baseline: 1.0062x; 1.0062x over previous
//
#include <hip/hip_runtime.h>
#include <stdint.h>

#define B_ 32
#define E_ 256
#define L_ 2048
#define D_ 256

#define BE 128             // e-rows per block
#define BD 256             // d-cols per block (full D)
#define BK 32              // k per LDS tile
#define KS 4               // k-split factor
#define KCHUNK (L_ / KS)   // 512
#define NKT (KCHUNK / BK)  // 16 k-steps per block

typedef __attribute__((ext_vector_type(2))) float  f32x2;
typedef __attribute__((ext_vector_type(4))) float  f32x4;
typedef __attribute__((ext_vector_type(4))) short  s16x4;
typedef __attribute__((ext_vector_type(8))) short  s16x8;

// 3-bit row keys XORed into the 16B-octet index of a 128B LDS row.
#define KEYA(row) ((((row) >> 1) & 3) | (((row) & 1) << 2))
#define KEYB(row) (((row) >> 1) & 7)

// fp32 -> (hi, lo) bf16 pair. hi = truncated bf16(x); lo = bf16(x - hi).
__device__ __forceinline__ void cvt_hilo1(float x, short &h, short &l) {
    unsigned u = __builtin_bit_cast(unsigned, x);
    h = (short)(u >> 16);
    float hf = __builtin_bit_cast(float, u & 0xFFFF0000u);
    unsigned r = __builtin_bit_cast(unsigned, x - hf);
    l = (short)(r >> 16);
}

__global__ void zero_out_kernel(f32x4* __restrict__ out) {
    out[(size_t)blockIdx.x * 256 + threadIdx.x] = f32x4{0.f, 0.f, 0.f, 0.f};
}

// ---- issue one k-tile's global loads into a register set (10 vmem instrs) ----
#define LOADT(PA, PB, K0)                                                      \
    {                                                                          \
        _Pragma("unroll")                                                      \
        for (int rr = 0; rr < 2; ++rr)                                         \
            PA[rr] = *(const f32x4*)(Ag + (size_t)(a_r + rr * 64) * L_ + (K0) + a_c4 * 4); \
        _Pragma("unroll")                                                      \
        for (int j = 0; j < 8; ++j)                                            \
            PB[j] = *(const f32x2*)(Sg + (size_t)((K0) + kb * 8 + j) * D_ + dp * 2); \
    }

// ---- convert a register set to bf16 hi/lo and stage into an LDS buffer ----
// (first use of PA/PB here gets the compiler's COUNTED vmcnt wait)
#define STAGE_CONV(AbN, BbN, PA, PB)                                           \
    {                                                                          \
        _Pragma("unroll")                                                      \
        for (int rr = 0; rr < 2; ++rr) {                                       \
            s16x4 h, l;                                                        \
            _Pragma("unroll")                                                  \
            for (int i = 0; i < 4; ++i) { short hh, ll; cvt_hilo1(PA[rr][i], hh, ll); h[i] = hh; l[i] = ll; } \
            *(s16x4*)&(AbN)[awo_h[rr]] = h;                                    \
            *(s16x4*)&(AbN)[awo_l[rr]] = l;                                    \
        }                                                                      \
        _Pragma("unroll")                                                      \
        for (int dd = 0; dd < 2; ++dd) {                                       \
            s16x8 h, l;                                                        \
            _Pragma("unroll")                                                  \
            for (int j = 0; j < 8; ++j) { short hh, ll; cvt_hilo1(PB[j][dd], hh, ll); h[j] = hh; l[j] = ll; } \
            *(s16x8*)&(BbN)[bwo_h[dd]] = h;                                    \
            *(s16x8*)&(BbN)[bwo_l[dd]] = l;                                    \
        }                                                                      \
    }

// lgkm-only drain + raw barrier: staging writes become visible, but the
// global-load queue (vmcnt) stays in flight across the barrier.
#define LGKM_BARRIER()                                                         \
    {                                                                          \
        asm volatile("s_waitcnt lgkmcnt(0)" ::: "memory");                     \
        __builtin_amdgcn_s_barrier();                                          \
        asm volatile("" ::: "memory");                                         \
    }

// ---- one k-step: frag reads -> convert(k+1) -> issue loads(k+3) ->
//      staging writes -> MFMA (writes drain under it) -> lgkm barrier ----
#define ITER(K, AbC, BbC, AbN, BbN, PA, PB)                                    \
    {                                                                          \
        s16x8 bh[4], bl[4], ah[4], al[4];                                      \
        _Pragma("unroll")                                                      \
        for (int ni = 0; ni < 4; ++ni) {                                       \
            bh[ni] = *(const s16x8*)&(BbC)[bro_h[ni]];                         \
            bl[ni] = *(const s16x8*)&(BbC)[bro_l[ni]];                         \
        }                                                                      \
        _Pragma("unroll")                                                      \
        for (int mi = 0; mi < 4; ++mi) {                                       \
            ah[mi] = *(const s16x8*)&(AbC)[aro_h[mi]];                         \
            al[mi] = *(const s16x8*)&(AbC)[aro_l[mi]];                         \
        }                                                                      \
        if ((K) + 1 < NKT) {                                                   \
            STAGE_CONV(AbN, BbN, PA, PB)                                       \
            if ((K) + 3 < NKT) LOADT(PA, PB, ((K) + 3) * BK)                   \
        }                                                                      \
        __builtin_amdgcn_s_setprio(1);                                         \
        _Pragma("unroll")                                                      \
        for (int mi = 0; mi < 4; ++mi)                                         \
            _Pragma("unroll")                                                  \
            for (int ni = 0; ni < 4; ++ni) {                                   \
                acc[mi][ni] = __builtin_amdgcn_mfma_f32_16x16x32_bf16(ah[mi], bh[ni], acc[mi][ni], 0, 0, 0); \
                acc[mi][ni] = __builtin_amdgcn_mfma_f32_16x16x32_bf16(ah[mi], bl[ni], acc[mi][ni], 0, 0, 0); \
                acc[mi][ni] = __builtin_amdgcn_mfma_f32_16x16x32_bf16(al[mi], bh[ni], acc[mi][ni], 0, 0, 0); \
            }                                                                  \
        __builtin_amdgcn_s_setprio(0);                                         \
        if ((K) + 1 < NKT) LGKM_BARRIER()                                      \
    }

__global__ __launch_bounds__(512, 2)
void mean_pool_kernel(const float* __restrict__ doc,
                      const float* __restrict__ emap,
                      const float* __restrict__ lens,
                      float* __restrict__ out) {
    __shared__ __align__(16) short As[2][BE][64];   // 32 KB
    __shared__ __align__(16) short Bs[2][BD][64];   // 64 KB
    __shared__ float lens_s[BE];

    const int t   = threadIdx.x;
    const int blk = blockIdx.x;
    const int ks  = blk & 3;
    const int e0  = ((blk >> 2) & 1) * BE;
    const int b   = blk >> 3;

    const float* Ag = emap + ((size_t)b * E_ + e0) * L_ + ks * KCHUNK;
    const float* Sg = doc  + (size_t)b * L_ * D_ + (size_t)ks * KCHUNK * D_;

    if (t < BE) lens_s[t] = lens[b * E_ + e0 + t];

    // ---- staging coords ----
    const int a_c4 = t & 7;      // k half-octet (4 floats)
    const int a_r  = t >> 3;     // e-rows a_r, a_r+64
    const int dp   = t & 127;    // d-pair index
    const int kb   = t >> 7;     // k-octet 0..3

    // ---- wave/MFMA coords: 8 waves as 2(e) x 4(d), wave tile 64x64 ----
    const int lane = t & 63;
    const int w    = t >> 6;
    const int eo   = (w & 1) * 64;
    const int dq   = (w >> 1) * 64;
    const int ml   = lane & 15;
    const int kg   = lane >> 4;

    // ---- precomputed LDS short-offsets ----
    int awo_h[2], awo_l[2];
    #pragma unroll
    for (int rr = 0; rr < 2; ++rr) {
        const int row = a_r + rr * 64, k = KEYA(row), hb = (a_c4 & 1) * 4;
        awo_h[rr] = row * 64 + ((((a_c4 >> 1)    ) ^ k) << 3) + hb;
        awo_l[rr] = row * 64 + ((((a_c4 >> 1) | 4) ^ k) << 3) + hb;
    }
    int bwo_h[2], bwo_l[2];
    #pragma unroll
    for (int dd = 0; dd < 2; ++dd) {
        const int row = dp * 2 + dd, k = KEYB(row);
        bwo_h[dd] = row * 64 + (((kb    ) ^ k) << 3);
        bwo_l[dd] = row * 64 + (((kb | 4) ^ k) << 3);
    }
    int aro_h[4], aro_l[4], bro_h[4], bro_l[4];
    #pragma unroll
    for (int i = 0; i < 4; ++i) {
        const int ar = eo + i * 16 + ml, ka = KEYA(ar);
        aro_h[i] = ar * 64 + (((kg    ) ^ ka) << 3);
        aro_l[i] = ar * 64 + (((kg | 4) ^ ka) << 3);
        const int br = dq + i * 16 + ml, kB = KEYB(br);
        bro_h[i] = br * 64 + (((kg    ) ^ kB) << 3);
        bro_l[i] = br * 64 + (((kg | 4) ^ kB) << 3);
    }

    f32x4 acc[4][4] = {};
    f32x4 paE[2], paO[2];
    f32x2 pbE[8], pbO[8];

    // ---- prologue: fill 2-deep pipeline; convert tile 0 ----
    LOADT(paE, pbE, 0)            // tile 0
    LOADT(paO, pbO, BK)           // tile 1
    STAGE_CONV(&As[0][0][0], &Bs[0][0][0], paE, pbE)   // counted vmcnt(10)
    LOADT(paE, pbE, 2 * BK)       // tile 2
    LGKM_BARRIER()

    // ---- main loop: 2x expansion => fully static buffer / reg-set indices ----
    for (int kt = 0; kt < NKT; kt += 2) {
        ITER(kt,     (&As[0][0][0]), (&Bs[0][0][0]), (&As[1][0][0]), (&Bs[1][0][0]), paO, pbO)
        ITER(kt + 1, (&As[1][0][0]), (&Bs[1][0][0]), (&As[0][0][0]), (&Bs[0][0][0]), paE, pbE)
    }

    // ---- epilogue: divide by entity_lens, accumulate k-split partials ----
    #pragma unroll
    for (int mi = 0; mi < 4; ++mi) {
        #pragma unroll
        for (int rr = 0; rr < 4; ++rr) {
            const int er = eo + mi * 16 + kg * 4 + rr;
            const float lv = lens_s[er];
            #pragma unroll
            for (int ni = 0; ni < 4; ++ni)
                atomicAdd(&out[((size_t)(b * E_ + e0 + er)) * D_ + dq + ni * 16 + ml],
                          acc[mi][ni][rr] / lv);
        }
    }
}

extern "C" void kernel_launch(void* const* d_in, const int* in_sizes, int n_in,
                              void* d_out, int out_size, void* d_ws, size_t ws_size,
                              hipStream_t stream) {
    const float* doc  = (const float*)d_in[0];   // [32][2048][256]
    const float* emap = (const float*)d_in[1];   // [32][256][2048]
    const float* lens = (const float*)d_in[2];   // [32][256]
    float* out = (float*)d_out;                  // [32][256][256]

    // zero the output (harness poisons it), then accumulate partials
    zero_out_kernel<<<dim3(out_size / (4 * 256)), dim3(256), 0, stream>>>((f32x4*)out);

    dim3 grid(B_ * (E_ / BE) * (D_ / BD) * KS);  // 256 workgroups, 1 per CU
    dim3 block(512);
    hipLaunchKernelGGL(mean_pool_kernel, grid, block, 0, stream,
                       doc, emap, lens, out);
}